// Round 4
// baseline (112.479 us; speedup 1.0000x reference)
//
#include <hip/hip_runtime.h>
#include <hip/hip_bf16.h>

// SINDy: theta(N,969) @ (C*mask)(969,16), plus l1 = mean|C*mask|.
// N=262144, latent=16, lib = 1 + 16 + 136 + 816 = 969 (pad K to 992 = 31*32).
// Strategy: bf16 MFMA 16x16x32. Each wave handles 64 rows; each lane builds the
// full theta row (compile-time-indexed products from z kept in registers),
// stages bf16 chunks through swizzled wave-private LDS, reads back as A-frags.
// B-frags (coefficients) are pre-swizzled into d_ws by a prep kernel.
//
// R4 change: bf16 pack via inline-asm v_cvt_pk_bf16_f32 (no builtin/header fn
// exists on gfx950/ROCm 7.2) — replaces the 9-op manual RNE pack that was
// ~2/3 of all VALU work.

#define LIB    969
#define KPAD   992
#define NCHUNK 31
#define NROWS  262144
#define NOUT   16

typedef __attribute__((ext_vector_type(8))) short bf16x8;
typedef __attribute__((ext_vector_type(4))) float f32x4;

struct Tbl { unsigned char a[KPAD]; unsigned char b[KPAD]; unsigned char c[KPAD]; };
constexpr Tbl make_tbl() {
  Tbl t{}; int n = 0;
  // order must match reference: [1, z_i, z_i z_j (i<=j), z_i z_j z_k (i<=j<=k)]
  t.a[n] = 16; t.b[n] = 16; t.c[n] = 16; n++;                       // 1
  for (int i = 0; i < 16; i++) { t.a[n] = (unsigned char)i; t.b[n] = 16; t.c[n] = 16; n++; }
  for (int i = 0; i < 16; i++)
    for (int j = i; j < 16; j++) { t.a[n] = (unsigned char)i; t.b[n] = (unsigned char)j; t.c[n] = 16; n++; }
  for (int i = 0; i < 16; i++)
    for (int j = i; j < 16; j++)
      for (int k = j; k < 16; k++) { t.a[n] = (unsigned char)i; t.b[n] = (unsigned char)j; t.c[n] = (unsigned char)k; n++; }
  for (; n < KPAD; n++) { t.a[n] = 16; t.b[n] = 16; t.c[n] = 16; }  // pad (coeff rows are 0)
  return t;
}
constexpr Tbl TBL = make_tbl();

// fp32 -> bf16 RNE, scalar (prep kernel only, not perf-critical)
__device__ inline unsigned short f2bf(float x) {
  unsigned int u = __builtin_bit_cast(unsigned int, x);
  u += 0x7fffu + ((u >> 16) & 1u);
  return (unsigned short)(u >> 16);
}
// packed pair fp32 -> 2x bf16 in one u32 (a -> low 16, b -> high 16), RNE
__device__ inline unsigned int pkbf(float a, float b) {
  unsigned int r;
  asm("v_cvt_pk_bf16_f32 %0, %1, %2" : "=v"(r) : "v"(a), "v"(b));
  return r;
}

// ---- prep: masked coeffs -> bf16 in B-fragment layout; L1 partial sums ----
// B-frag layout: lane l of the MFMA wants C[k = 8*(l>>4)+m][col = l&15] as 8
// contiguous bf16. Store element (t, o) with t = slice*32 + g*8 + m at
// ushort index ((slice*4 + g)*16 + o)*8 + m.
__global__ __launch_bounds__(256) void prep_kernel(const float* __restrict__ C,
                                                   const float* __restrict__ M,
                                                   unsigned short* __restrict__ Cb,
                                                   float* __restrict__ acc) {
  const int idx = blockIdx.x * 256 + threadIdx.x;   // 0 .. 15871 (= KPAD*16)
  const int t = idx >> 4, o = idx & 15;
  float v = 0.f;
  if (t < LIB) v = C[t * 16 + o] * M[t * 16 + o];
  const int slice = t >> 5, g = (t >> 3) & 3, m = t & 7;
  Cb[((slice * 4 + g) * 16 + o) * 8 + m] = f2bf(v);
  // L1: wave-reduce |v| then one atomic per wave
  float s = fabsf(v);
  #pragma unroll
  for (int off = 32; off > 0; off >>= 1) s += __shfl_down(s, off);
  if ((threadIdx.x & 63) == 0) atomicAdd(acc, s);
}

// swizzled byte offset of (row r, 16B-quad q) in a [64 rows][64 B] tile:
// every 8 consecutive rows cover all 8 16B-slots of a 128B bank span -> conflict-free
__device__ inline int swz(int r, int q) { return r * 64 + ((q ^ ((r >> 1) & 3)) << 4); }

__global__ __launch_bounds__(256) void sindy_kernel(const float* __restrict__ z,
                                                    const unsigned short* __restrict__ Cb,
                                                    const float* __restrict__ acc,
                                                    float* __restrict__ out) {
  __shared__ uint4 stage4[4][256];                    // 4 KB per wave, wave-private
  char* stage = (char*)&stage4[threadIdx.x >> 6][0];
  const int lane = threadIdx.x & 63;
  const int g = lane >> 4;                            // k-group for MFMA frags
  const int lr = lane & 15;                           // row-in-tile / col
  const int rowBase = blockIdx.x * 256 + (threadIdx.x >> 6) * 64;

  // lane's row of z, plus sentinel 1.0 at index 16
  float z17[17];
  {
    const float4* z4 = (const float4*)z;
    const int r = rowBase + lane;
    #pragma unroll
    for (int c4 = 0; c4 < 4; c4++) {
      float4 v = z4[r * 4 + c4];
      z17[c4 * 4 + 0] = v.x; z17[c4 * 4 + 1] = v.y;
      z17[c4 * 4 + 2] = v.z; z17[c4 * 4 + 3] = v.w;
    }
    z17[16] = 1.0f;
  }

  f32x4 acc4[4] = {{0.f,0.f,0.f,0.f},{0.f,0.f,0.f,0.f},{0.f,0.f,0.f,0.f},{0.f,0.f,0.f,0.f}};

  #pragma unroll
  for (int c = 0; c < NCHUNK; c++) {
    // build 32 library entries for this K-chunk (all indices compile-time)
    float th[32];
    #pragma unroll
    for (int m = 0; m < 32; m++) {
      const int t = c * 32 + m;
      th[m] = (z17[TBL.a[t]] * z17[TBL.b[t]]) * z17[TBL.c[t]];
    }
    unsigned int pk[16];
    #pragma unroll
    for (int m = 0; m < 16; m++) pk[m] = pkbf(th[2 * m], th[2 * m + 1]);
    // stage: lane = row, 4x ds_write_b128 (swizzled)
    #pragma unroll
    for (int q = 0; q < 4; q++)
      *(uint4*)(stage + swz(lane, q)) = make_uint4(pk[4*q], pk[4*q+1], pk[4*q+2], pk[4*q+3]);

    // B-frag: one coalesced 16B global read (L2-resident, 31 KB total)
    bf16x8 bfrag = *(const bf16x8*)(Cb + ((c * 4 + g) * 16 + lr) * 8);

    // 4 row-subtiles of 16: A-frag = row 16s+lr, k-quad g (swizzled), then MFMA
    #pragma unroll
    for (int s = 0; s < 4; s++) {
      const int r = 16 * s + lr;
      bf16x8 afrag = *(const bf16x8*)(stage + swz(r, g));
      acc4[s] = __builtin_amdgcn_mfma_f32_16x16x32_bf16(afrag, bfrag, acc4[s], 0, 0, 0);
    }
  }

  // C/D layout (m89-verified): col = lane&15, row = 4*(lane>>4) + reg
  #pragma unroll
  for (int s = 0; s < 4; s++) {
    #pragma unroll
    for (int p = 0; p < 4; p++)
      out[(rowBase + 16 * s + 4 * g + p) * 16 + lr] = acc4[s][p];
  }

  if (blockIdx.x == 0 && threadIdx.x == 0)
    out[NROWS * NOUT] = acc[0] * (1.0f / 15504.0f);   // mean over 969*16
}

extern "C" void kernel_launch(void* const* d_in, const int* in_sizes, int n_in,
                              void* d_out, int out_size, void* d_ws, size_t ws_size,
                              hipStream_t stream) {
  const float* z = (const float*)d_in[0];
  const float* C = (const float*)d_in[1];
  const float* M = (const float*)d_in[2];
  float* out = (float*)d_out;
  float* acc = (float*)d_ws;                          // [0]: L1 accumulator
  unsigned short* Cb = (unsigned short*)((char*)d_ws + 64); // 31744 B coeff tile

  (void)hipMemsetAsync(d_ws, 0, 4, stream);           // zero L1 accumulator
  prep_kernel<<<KPAD * 16 / 256, 256, 0, stream>>>(C, M, Cb, acc);
  sindy_kernel<<<NROWS / 256, 256, 0, stream>>>(z, Cb, acc, out);
}

// Round 5
// 54.612 us; speedup vs baseline: 2.0596x; 2.0596x over previous
//
#include <hip/hip_runtime.h>
#include <hip/hip_bf16.h>

// SINDy: theta(N,969) @ (C*mask)(969,16), plus l1 = mean|C*mask|.
// N=262144, latent=16, lib = 1 + 16 + 136 + 816 = 969; K padded to 992 = 31*32.
//
// R5 redesign — no LDS: exploit the rotation i -> i+4 (mod 16) on latent
// indices. The 969 library entries fall into orbits under this Z4 action
// (204 triple orbits, 32+4 pair orbits, 4 linear, 1 const = 245 reps).
// K-slot (chunk c, slice g, elem m) holds orbit member g of rep s=c*8+m.
// Lane l (slice g = l>>4, col/row o = l&15) computes its A-fragment entries
// directly as products of ROTATED z: zrot[m] = z[(m+4g)&15], with all product
// indices compile-time (the same 248 expressions for every lane). Coefficients
// are gathered into the matching order by the prep kernel via a constexpr
// slot->library-index table (duplicate orbit members get coeff 0).
// Each wave = one 16x16 out tile, 31 MFMAs, zero LDS traffic.

#define LIB    969
#define NSLOT  248
#define NCHUNK 31
#define NROWS  262144
#define NOUT   16

typedef __attribute__((ext_vector_type(8))) short bf16x8;
typedef __attribute__((ext_vector_type(4))) float f32x4;

struct Maps {
  unsigned char a[NSLOT], b[NSLOT], c[NSLOT];  // zrot indices (16 = sentinel 1.0)
  short l[NSLOT][4];                           // library row per slice g, or -1
};

constexpr Maps build_maps() {
  Maps M{};
  int n = 0;
  // const term: product 1 in every slice; coeff only at g=0
  M.a[n] = 16; M.b[n] = 16; M.c[n] = 16;
  M.l[n][0] = 0; M.l[n][1] = -1; M.l[n][2] = -1; M.l[n][3] = -1; n++;
  // linear orbits: reps a0 = 0..3, member g = z_{(a0+4g)&15}
  for (int a0 = 0; a0 < 4; a0++) {
    M.a[n] = (unsigned char)a0; M.b[n] = 16; M.c[n] = 16;
    for (int g = 0; g < 4; g++) M.l[n][g] = (short)(1 + ((a0 + 4 * g) & 15));
    n++;
  }
  // pair orbits
  bool pv[16][16] = {};
  for (int i = 0; i < 16; i++)
    for (int j = i; j < 16; j++) {
      if (pv[i][j]) continue;
      M.a[n] = (unsigned char)i; M.b[n] = (unsigned char)j; M.c[n] = 16;
      int mi[4], mj[4];
      for (int g = 0; g < 4; g++) {
        int x = (i + 4 * g) & 15, y = (j + 4 * g) & 15;
        int lo = x < y ? x : y, hi = x < y ? y : x;
        mi[g] = lo; mj[g] = hi; pv[lo][hi] = true;
      }
      for (int g = 0; g < 4; g++) {
        bool dup = false;
        for (int h = 0; h < g; h++) if (mi[h] == mi[g] && mj[h] == mj[g]) dup = true;
        M.l[n][g] = dup ? (short)-1
                        : (short)(17 + mi[g] * 16 - mi[g] * (mi[g] - 1) / 2 + (mj[g] - mi[g]));
      }
      n++;
    }
  // triple orbits (all size 4)
  bool tv[16][16][16] = {};
  for (int i = 0; i < 16; i++)
    for (int j = i; j < 16; j++)
      for (int k = j; k < 16; k++) {
        if (tv[i][j][k]) continue;
        M.a[n] = (unsigned char)i; M.b[n] = (unsigned char)j; M.c[n] = (unsigned char)k;
        int ti[4], tj[4], tk[4];
        for (int g = 0; g < 4; g++) {
          int x = (i + 4 * g) & 15, y = (j + 4 * g) & 15, w = (k + 4 * g) & 15, t;
          if (x > y) { t = x; x = y; y = t; }
          if (y > w) { t = y; y = w; w = t; }
          if (x > y) { t = x; x = y; y = t; }
          ti[g] = x; tj[g] = y; tk[g] = w; tv[x][y][w] = true;
        }
        for (int g = 0; g < 4; g++) {
          bool dup = false;
          for (int h = 0; h < g; h++)
            if (ti[h] == ti[g] && tj[h] == tj[g] && tk[h] == tk[g]) dup = true;
          if (dup) { M.l[n][g] = -1; continue; }
          int i2 = ti[g], j2 = tj[g], k2 = tk[g];
          int base = 0;
          for (int a2 = 0; a2 < i2; a2++) base += (16 - a2) * (17 - a2) / 2;
          int off = (j2 - i2) * (16 - i2) - (j2 - i2) * (j2 - i2 - 1) / 2 + (k2 - j2);
          M.l[n][g] = (short)(153 + base + off);
        }
        n++;
      }
  // pad to 248 slots (product 1, coeff 0 everywhere)
  for (; n < NSLOT; n++) {
    M.a[n] = 16; M.b[n] = 16; M.c[n] = 16;
    M.l[n][0] = M.l[n][1] = M.l[n][2] = M.l[n][3] = -1;
  }
  return M;
}
constexpr Maps MP = build_maps();

// ---- prep: gather masked coeffs (bf16) into B-fragment/slot order; L1 sum ----
// B-frag: lane l reads 8 contiguous bf16 at ((c*4+g)*16 + o)*8, element m.
__global__ __launch_bounds__(256) void prep_kernel(const float* __restrict__ C,
                                                   const float* __restrict__ M,
                                                   unsigned short* __restrict__ Cb,
                                                   float* __restrict__ acc) {
  const int idx = blockIdx.x * 256 + threadIdx.x;   // 0 .. 15871 = NSLOT*4*16
  const int s = idx >> 6, g = (idx >> 4) & 3, o = idx & 15;
  const int li = MP.l[s][g];
  float v = 0.f;
  if (li >= 0) v = C[li * 16 + o] * M[li * 16 + o];
  __hip_bfloat16 h = __float2bfloat16(v);
  unsigned short u; __builtin_memcpy(&u, &h, 2);
  Cb[(((s >> 3) * 4 + g) * 16 + o) * 8 + (s & 7)] = u;
  float t = fabsf(v);
  #pragma unroll
  for (int off = 32; off > 0; off >>= 1) t += __shfl_down(t, off);
  if ((threadIdx.x & 63) == 0) atomicAdd(acc, t);
}

__global__ __launch_bounds__(256) void sindy_kernel(const float* __restrict__ z,
                                                    const unsigned short* __restrict__ Cb,
                                                    const float* __restrict__ acc,
                                                    float* __restrict__ out) {
  const int lane = threadIdx.x & 63;
  const int g = lane >> 4;                          // k-slice
  const int o = lane & 15;                          // row-in-tile (A) / out col (B)
  const int rowBase = blockIdx.x * 64 + (threadIdx.x >> 6) * 16;
  const int r = rowBase + o;

  // load z-row r (each row read by 4 lanes; L1-served)
  float z17[17];
  {
    const float4* z4 = (const float4*)z;
    #pragma unroll
    for (int c4 = 0; c4 < 4; c4++) {
      float4 v = z4[r * 4 + c4];
      z17[c4 * 4 + 0] = v.x; z17[c4 * 4 + 1] = v.y;
      z17[c4 * 4 + 2] = v.z; z17[c4 * 4 + 3] = v.w;
    }
    z17[16] = 1.0f;
  }
  // rotate by 4g with two compile-time-indexed cndmask layers
  const bool b0 = (g & 1) != 0, b1 = (g & 2) != 0;
  float t16[16], zr[17];
  #pragma unroll
  for (int m = 0; m < 16; m++) t16[m] = b0 ? z17[(m + 4) & 15] : z17[m];
  #pragma unroll
  for (int m = 0; m < 16; m++) zr[m] = b1 ? t16[(m + 8) & 15] : t16[m];
  zr[16] = 1.0f;

  f32x4 acc4 = {0.f, 0.f, 0.f, 0.f};
  #pragma unroll
  for (int c = 0; c < NCHUNK; c++) {
    bf16x8 af;
    #pragma unroll
    for (int m = 0; m < 8; m++) {
      const int s = c * 8 + m;
      float th = (zr[MP.a[s]] * zr[MP.b[s]]) * zr[MP.c[s]];
      __hip_bfloat16 h = __float2bfloat16(th);       // scalar cast: compiler fuses to cvt_pk
      unsigned short u; __builtin_memcpy(&u, &h, 2);
      af[m] = (short)u;
    }
    bf16x8 bfrag = *(const bf16x8*)(Cb + ((c * 4 + g) * 16 + o) * 8);
    acc4 = __builtin_amdgcn_mfma_f32_16x16x32_bf16(af, bfrag, acc4, 0, 0, 0);
  }

  // C/D layout (m89-verified): col = lane&15, row = 4*(lane>>4) + reg
  #pragma unroll
  for (int p = 0; p < 4; p++)
    out[(rowBase + 4 * g + p) * 16 + o] = acc4[p];

  if (blockIdx.x == 0 && threadIdx.x == 0)
    out[NROWS * NOUT] = acc[0] * (1.0f / 15504.0f);  // mean over 969*16
}

extern "C" void kernel_launch(void* const* d_in, const int* in_sizes, int n_in,
                              void* d_out, int out_size, void* d_ws, size_t ws_size,
                              hipStream_t stream) {
  const float* z = (const float*)d_in[0];
  const float* C = (const float*)d_in[1];
  const float* M = (const float*)d_in[2];
  float* out = (float*)d_out;
  float* acc = (float*)d_ws;                          // [0]: L1 accumulator
  unsigned short* Cb = (unsigned short*)((char*)d_ws + 64); // 31744 B coeff slots

  (void)hipMemsetAsync(d_ws, 0, 4, stream);           // zero L1 accumulator
  prep_kernel<<<NSLOT * 4 * 16 / 256, 256, 0, stream>>>(C, M, Cb, acc);
  sindy_kernel<<<NROWS / 64, 256, 0, stream>>>(z, Cb, acc, out);
}